// Round 1
// baseline (976.336 us; speedup 1.0000x reference)
//
#include <hip/hip_runtime.h>
#include <math.h>

#define PW 32
#define PL 64
#define PK 512
#define PN 64
// vectors (replica configurations) total: PW*PL*PK = 1,048,576

// ---------------- Kernel 1: energies ----------------
// One wave per chunk of VPW vectors, all belonging to the same w.
// Lane j holds Q[w][:, j] (column) as f64 in registers (128 VGPRs).
// Per vector: ballot -> wave-uniform 64-bit subset mask in SGPRs,
// statically-unrolled uniform branches accumulate ~32 f64 adds.
constexpr int VPW = 64;

__global__ __launch_bounds__(256) void energies_kernel(
    const float* __restrict__ states, const float* __restrict__ Q,
    float* __restrict__ e_out, double* __restrict__ e64)
{
    const int wave = (blockIdx.x * blockDim.x + threadIdx.x) >> 6;
    const int lane = threadIdx.x & 63;
    const int waves_per_w = (PL * PK) / VPW;   // 512
    const int w = wave / waves_per_w;
    const int chunk = wave % waves_per_w;

    // Load this lane's Q column into f64 registers.
    const float* Qw = Q + (long)w * PN * PN;
    double qd[64];
#pragma unroll
    for (int i = 0; i < 64; ++i) qd[i] = (double)Qw[i * 64 + lane];

    const long base_v = (long)w * (PL * PK) + (long)chunk * VPW;
    const float* sp = states + base_v * PN + lane;

    for (int t = 0; t < VPW; ++t) {
        const float s = sp[(long)t * PN];           // coalesced 256B wave load
        const bool bit = (s != 0.0f);
        const unsigned long long m = __ballot(bit); // wave-uniform subset mask

        double acc = 0.0;                           // colsum_j = sum_{i in S} Q[i][j]
#pragma unroll
        for (int i = 0; i < 64; ++i) {
            if (m & (1ull << i)) acc += qd[i];
        }

        double e = bit ? acc : 0.0;                 // only columns j in S count
        // wave-wide f64 sum
#pragma unroll
        for (int off = 32; off > 0; off >>= 1)
            e += __shfl_down(e, off, 64);

        if (lane == 0) {
            e64[base_v + t]  = e;
            e_out[base_v + t] = (float)e;
        }
    }
}

// ---------------- Kernel 2: exchange masks ----------------
__global__ __launch_bounds__(256) void mask_kernel(
    const double* __restrict__ e64, const float* __restrict__ beta,
    const float* __restrict__ u, unsigned char* __restrict__ mask)
{
    const int idx = blockIdx.x * blockDim.x + threadIdx.x;
    if (idx >= PW * (PL - 1) * PK) return;
    const int k = idx % PK;
    const int m = (idx / PK) % (PL - 1);
    const int w = idx / (PK * (PL - 1));
    const long e1 = ((long)w * PL + m) * PK + k;
    const double db = (double)beta[m + 1] - (double)beta[m];
    const double delta = (e64[e1 + PK] - e64[e1]) * db;
    mask[idx] = ((double)u[idx] < exp(delta)) ? 1 : 0;
}

// ---------------- Kernel 3: masked replica swap ----------------
// new[w,0]   = mask[w,0]   ? s[w,1]   : s[w,0]
// new[w,l>0] = mask[w,l-1] ? s[w,l-1] : s[w,l]
// One thread per float4 (16 B) of output.
__global__ __launch_bounds__(256) void swap_kernel(
    const float* __restrict__ states, const unsigned char* __restrict__ mask,
    float* __restrict__ out)
{
    const long idx = (long)blockIdx.x * blockDim.x + threadIdx.x;  // float4 units
    const int j4 = (int)(idx & 15);
    const long row = idx >> 4;                 // (w*L + l)*K + k
    const int k = (int)(row % PK);
    const int l = (int)((row / PK) % PL);
    const int w = (int)(row / (PK * PL));

    const int ml = (l == 0) ? 0 : (l - 1);
    const unsigned char mk = mask[((long)w * (PL - 1) + ml) * PK + k];
    int src_l;
    if (l == 0) src_l = mk ? 1 : 0;
    else        src_l = mk ? (l - 1) : l;

    const float4* src = (const float4*)(states + (((long)w * PL + src_l) * PK + k) * PN);
    float4* dst = (float4*)(out + row * PN);
    dst[j4] = src[j4];
}

extern "C" void kernel_launch(void* const* d_in, const int* in_sizes, int n_in,
                              void* d_out, int out_size, void* d_ws, size_t ws_size,
                              hipStream_t stream) {
    const float* states = (const float*)d_in[0];
    const float* Q      = (const float*)d_in[1];
    const float* beta   = (const float*)d_in[2];
    const float* u      = (const float*)d_in[3];

    float* e_out      = (float*)d_out;
    float* new_states = (float*)d_out + (long)PW * PL * PK;

    double* e64 = (double*)d_ws;
    unsigned char* mask = (unsigned char*)d_ws + sizeof(double) * (long)PW * PL * PK;

    // K1: 32 w * 512 waves = 16384 waves = 1,048,576 threads
    energies_kernel<<<4096, 256, 0, stream>>>(states, Q, e_out, e64);

    const int nmask = PW * (PL - 1) * PK;
    mask_kernel<<<(nmask + 255) / 256, 256, 0, stream>>>(e64, beta, u, mask);

    // K3: W*L*K*16 float4 threads = 16,777,216 -> 65536 blocks
    swap_kernel<<<65536, 256, 0, stream>>>(states, mask, new_states);
}

// Round 3
// 835.762 us; speedup vs baseline: 1.1682x; 1.1682x over previous
//
#include <hip/hip_runtime.h>
#include <math.h>

#define PW 32
#define PL 64
#define PK 512
#define PN 64
// vectors (replica configurations) total: PW*PL*PK = 1,048,576

// 0/1 mask bit -> f64 1.0/0.0 via scalar cselect (bit pattern of 1.0)
__device__ __forceinline__ double selbit(unsigned long long m, int i) {
    unsigned long long d = ((m >> i) & 1ull) ? 0x3FF0000000000000ull : 0ull;
    return __builtin_bit_cast(double, d);
}

// ---------------- Kernel 1: energies ----------------
// One wave per chunk of VPW vectors (same w). Lane j holds Q[w][:, j]
// (column) as f64 in registers. Per vector: ballot -> wave-uniform mask in
// SGPRs; 64 branch-free v_fma_f64 on 4 independent accumulator chains.
constexpr int VPW = 64;

__global__ __launch_bounds__(256, 3) void energies_kernel(
    const float* __restrict__ states, const float* __restrict__ Q,
    float* __restrict__ e_out, double* __restrict__ e64)
{
    const int wave = (blockIdx.x * blockDim.x + threadIdx.x) >> 6;
    const int lane = threadIdx.x & 63;
    const int waves_per_w = (PL * PK) / VPW;   // 512
    const int w = wave / waves_per_w;
    const int chunk = wave % waves_per_w;

    // Lane j's Q column in f64 registers (128 VGPRs).
    const float* Qw = Q + (long)w * PN * PN;
    double qd[64];
#pragma unroll
    for (int i = 0; i < 64; ++i) qd[i] = (double)Qw[i * 64 + lane];

    const long base_v = (long)w * (PL * PK) + (long)chunk * VPW;
    const float* sp = states + base_v * PN + lane;

    float s = sp[0];
    for (int t = 0; t < VPW; ++t) {
        // prefetch next vector's element (independent; scheduler hoists it)
        float snext = (t + 1 < VPW) ? sp[(long)(t + 1) * PN] : 0.0f;

        const unsigned long long m = __ballot(s != 0.0f); // wave-uniform mask

        double a0 = 0.0, a1 = 0.0, a2 = 0.0, a3 = 0.0;
#pragma unroll
        for (int i = 0; i < 64; i += 4) {
            a0 = __builtin_fma(selbit(m, i + 0), qd[i + 0], a0);
            a1 = __builtin_fma(selbit(m, i + 1), qd[i + 1], a1);
            a2 = __builtin_fma(selbit(m, i + 2), qd[i + 2], a2);
            a3 = __builtin_fma(selbit(m, i + 3), qd[i + 3], a3);
        }
        const double colsum = (a0 + a1) + (a2 + a3);

        // lane j contributes only if s_j != 0 ; s is exactly 0.0f or 1.0f
        double e = colsum * (double)s;
#pragma unroll
        for (int off = 32; off > 0; off >>= 1)
            e += __shfl_down(e, off, 64);

        if (lane == 0) {
            e64[base_v + t]   = e;
            e_out[base_v + t] = (float)e;
        }
        s = snext;
    }
}

// ---------------- Kernel 2: exchange masks ----------------
__global__ __launch_bounds__(256) void mask_kernel(
    const double* __restrict__ e64, const float* __restrict__ beta,
    const float* __restrict__ u, unsigned char* __restrict__ mask)
{
    const int idx = blockIdx.x * blockDim.x + threadIdx.x;
    if (idx >= PW * (PL - 1) * PK) return;
    const int k = idx % PK;
    const int m = (idx / PK) % (PL - 1);
    const int w = idx / (PK * (PL - 1));
    const long e1 = ((long)w * PL + m) * PK + k;
    const double db = (double)beta[m + 1] - (double)beta[m];
    const double delta = (e64[e1 + PK] - e64[e1]) * db;
    mask[idx] = ((double)u[idx] < exp(delta)) ? 1 : 0;
}

// ---------------- Kernel 3: masked replica swap ----------------
// new[w,0]   = mask[w,0]   ? s[w,1]   : s[w,0]
// new[w,l>0] = mask[w,l-1] ? s[w,l-1] : s[w,l]
// Block handles 32 consecutive rows (same w,l; k 32-aligned). Source-replica
// indices staged in LDS once; then independent, fully-coalesced float4 copies.
// Total rows = W*L*K = 1,048,576 -> grid must be 32768 blocks (NOT 65536 —
// round-2 crash was an OOB from the doubled grid).
__global__ __launch_bounds__(256) void swap_kernel(
    const float* __restrict__ states, const unsigned char* __restrict__ mask,
    float* __restrict__ out)
{
    const long rowBase = (long)blockIdx.x * 32;     // (w*L + l)*K + k0
    const int w  = (int)(rowBase >> 15);            // / (L*K)
    const int l  = (int)((rowBase >> 9) & 63);
    const int k0 = (int)(rowBase & 511);

    __shared__ int srcl[32];
    const int tid = threadIdx.x;
    if (tid < 32) {
        const int k = k0 + tid;
        int src;
        if (l == 0) {
            const unsigned char mk = mask[(long)w * (PL - 1) * PK + k];
            src = mk ? 1 : 0;
        } else {
            const unsigned char mk = mask[((long)w * (PL - 1) + (l - 1)) * PK + k];
            src = mk ? (l - 1) : l;
        }
        srcl[tid] = src;
    }
    __syncthreads();

    const int j4 = tid & 15;
    const int r0 = tid >> 4;                        // 0..15
#pragma unroll
    for (int h = 0; h < 2; ++h) {
        const int r = r0 + h * 16;                  // row within block, 0..31
        const int k = k0 + r;
        const int sl = srcl[r];
        const float4* srcp = (const float4*)(states + (((long)w * PL + sl) * PK + k) * PN);
        float4*       dstp = (float4*)(out + (rowBase + r) * PN);
        dstp[j4] = srcp[j4];
    }
}

extern "C" void kernel_launch(void* const* d_in, const int* in_sizes, int n_in,
                              void* d_out, int out_size, void* d_ws, size_t ws_size,
                              hipStream_t stream) {
    const float* states = (const float*)d_in[0];
    const float* Q      = (const float*)d_in[1];
    const float* beta   = (const float*)d_in[2];
    const float* u      = (const float*)d_in[3];

    float* e_out      = (float*)d_out;
    float* new_states = (float*)d_out + (long)PW * PL * PK;

    double* e64 = (double*)d_ws;
    unsigned char* mask = (unsigned char*)d_ws + sizeof(double) * (long)PW * PL * PK;

    // K1: 32 w * 512 chunk-waves = 16384 waves -> 4096 blocks of 256
    energies_kernel<<<4096, 256, 0, stream>>>(states, Q, e_out, e64);

    const int nmask = PW * (PL - 1) * PK;
    mask_kernel<<<(nmask + 255) / 256, 256, 0, stream>>>(e64, beta, u, mask);

    // K3: 1,048,576 rows / 32 per block = 32768 blocks
    swap_kernel<<<32768, 256, 0, stream>>>(states, mask, new_states);
}